// Round 11
// baseline (120.714 us; speedup 1.0000x reference)
//
#include <hip/hip_runtime.h>

#define NSEQ   24
#define NBOX   196
#define NCTX   196
#define MAXLEN 6
#define EPSV   1e-6f
#define BS     32

#define TILES  25    // i-tiles per batch; 8 waves/block, 1 i per wave
#define K1T    512
#define NB4    49    // float4 chunks per 196-row
#define ROWP   200   // padded cae row: 196 data + 4 zeros (sentinel idx 196)

#define SPO_ELEMS  ((size_t)BS * NSEQ * NBOX * NCTX)        // 29,503,488
#define SPO16_B    (SPO_ELEMS * 2)                          // 59,006,976 B
#define MIDX_B     ((size_t)BS * NBOX * NCTX)               // 1,229,312 B
#define ARAW_B     ((size_t)BS * NBOX * 4)

typedef unsigned short us8 __attribute__((ext_vector_type(8)));

// ---- spo f32 -> bf16 (RNE), fully parallel stream
__global__ __launch_bounds__(256) void conv_spo(
    const float* __restrict__ spo, unsigned short* __restrict__ spo16)
{
    const size_t total8 = SPO_ELEMS / 8;
    for (size_t t = (size_t)blockIdx.x * 256 + threadIdx.x; t < total8;
         t += (size_t)gridDim.x * 256) {
        const uint4 a = ((const uint4*)spo)[2 * t];
        const uint4 b = ((const uint4*)spo)[2 * t + 1];
        us8 o;
        o[0] = (unsigned short)((a.x + 0x7FFFu + ((a.x >> 16) & 1u)) >> 16);
        o[1] = (unsigned short)((a.y + 0x7FFFu + ((a.y >> 16) & 1u)) >> 16);
        o[2] = (unsigned short)((a.z + 0x7FFFu + ((a.z >> 16) & 1u)) >> 16);
        o[3] = (unsigned short)((a.w + 0x7FFFu + ((a.w >> 16) & 1u)) >> 16);
        o[4] = (unsigned short)((b.x + 0x7FFFu + ((b.x >> 16) & 1u)) >> 16);
        o[5] = (unsigned short)((b.y + 0x7FFFu + ((b.y >> 16) & 1u)) >> 16);
        o[6] = (unsigned short)((b.z + 0x7FFFu + ((b.z >> 16) & 1u)) >> 16);
        o[7] = (unsigned short)((b.w + 0x7FFFu + ((b.w >> 16) & 1u)) >> 16);
        ((us8*)spo16)[t] = o;
    }
}

__device__ __forceinline__ float bf(unsigned short u) {
    return __uint_as_float((unsigned)u << 16);
}

// mode: 0 = f32 spo + per-step midx from ctx+rm (fallback, ws too small)
//       1 = bf16 spo, compute+store u8 midx (step 0)
//       2 = bf16 spo, load u8 midx (steps 1..5)
__global__ __launch_bounds__(K1T, 6) void step_compute(
    const float* __restrict__ src,      // ent (step 0) or ea
    float*       __restrict__ ea,       // [BS,NSEQ,NBOX] (d_out)
    const float* __restrict__ spo,      // [BS,NSEQ,NBOX,NCTX] f32
    const unsigned short* __restrict__ spo16,  // ws bf16 copy
    const int*   __restrict__ ctx,      // [BS,NBOX,NCTX]
    const int*   __restrict__ roi_cls,  // [BS,NBOX]
    const float* __restrict__ rm,       // [BS,NBOX,NCTX]
    const int*   __restrict__ trav,     // [BS,MAXLEN]
    const int*   __restrict__ adj,      // [BS,NSEQ,NSEQ]
    unsigned char* __restrict__ midx,   // ws
    float*       __restrict__ araw,     // ws [BS,NBOX]
    int step, int mode)
{
    const int b    = blockIdx.x / TILES;
    const int tile = blockIdx.x % TILES;
    const int tid  = threadIdx.x;
    const int wave = tid >> 6;
    const int lane = tid & 63;

    __shared__ __align__(16) float cae[NSEQ][ROWP];
    __shared__ int s_childJ[NSEQ];

    // ---- fused ent -> ea copy (step 0; nothing reads ea this dispatch)
    if (step == 0) {
        const int total4 = BS * NSEQ * NBOX / 4;
        int idx = blockIdx.x * K1T + tid;
        if (idx < total4) ((float4*)ea)[idx] = ((const float4*)src)[idx];
    }

    // ---- wave-parallel adjacency parse (full exec)
    const int p = trav[b * MAXLEN + step];
    int e = -1;
    if (p >= 0 && lane < NSEQ)
        e = adj[((size_t)b * NSEQ + p) * NSEQ + lane];
    const unsigned long long mask = __ballot(e >= 0);
    const int nch = __popcll(mask);
    int ec = 0;
    if (nch > 0) {
        unsigned long long m = mask;
        const int lim = (lane < NSEQ) ? lane : NSEQ;
        for (int k = 0; k < lim; ++k) m &= (m - 1);
        const int j0 = __ffsll(mask) - 1;
        const int jn = m ? (__ffsll(m) - 1) : j0;
        const int jc = (lane < nch) ? jn : j0;   // lanes >= nch: child 0 (pad)
        ec = __shfl(e, jc);                      // full-exec shfl: safe
        if (wave == 0 && lane < nch) s_childJ[lane] = jc;
    }

    // ---- per-wave i; mask-index vector (built/stored/loaded BEFORE any return
    //      so step-0 writes midx for all i even when nch==0)
    const int i = tile * 8 + wave;
    int4 mi = make_int4(NBOX, NBOX, NBOX, NBOX);
    if (i < NBOX && lane < NB4) {
        const size_t bi = (size_t)b * NBOX + i;
        if (mode == 2) {
            const uchar4 u = ((const uchar4*)(midx + bi * NCTX))[lane];
            mi = make_int4(u.x, u.y, u.z, u.w);
        } else {
            const int4   ix = ((const int4*)  (ctx + bi * NCTX))[lane];
            const float4 m4 = ((const float4*)(rm  + bi * NCTX))[lane];
            mi.x = (m4.x != 0.f) ? ix.x : NBOX;
            mi.y = (m4.y != 0.f) ? ix.y : NBOX;
            mi.z = (m4.z != 0.f) ? ix.z : NBOX;
            mi.w = (m4.w != 0.f) ? ix.w : NBOX;
            if (mode == 1)
                ((uchar4*)(midx + bi * NCTX))[lane] =
                    make_uchar4((unsigned char)mi.x, (unsigned char)mi.y,
                                (unsigned char)mi.z, (unsigned char)mi.w);
        }
    }

    if (nch == 0) return;   // uniform across block; no barrier crossed yet

    __syncthreads();        // s_childJ visible

    // ---- stage child rows * kcls into LDS (float4; quad 49 writes zero pad)
    for (int n = wave; n < nch; n += 8) {
        const int j = s_childJ[n];
        if (lane < 50) {
            float4 v = make_float4(0.f, 0.f, 0.f, 0.f);
            if (lane < NB4) {
                const float4 e4 = ((const float4*)(src + ((size_t)b * NSEQ + j) * NBOX))[lane];
                const int4   r4 = ((const int4*)(roi_cls + b * NBOX))[lane];
                v.x = (r4.x != -1) ? e4.x : 0.f;
                v.y = (r4.y != -1) ? e4.y : 0.f;
                v.z = (r4.z != -1) ? e4.z : 0.f;
                v.w = (r4.w != -1) ? e4.w : 0.f;
            }
            ((float4*)&cae[n][0])[lane] = v;
        }
    }
    __syncthreads();

    // ---- gather-dot: one i per wave, 3-deep rotating spo prefetch
    if (i < NBOX) {
        float acc = 0.f;
        if (lane < NB4) {
            const size_t st = (size_t)NBOX * NCTX;
            const int e0 = __shfl(ec, 0), e1 = __shfl(ec, 1), e2 = __shfl(ec, 2);
            float4 a4 = make_float4(0.f, 0.f, 0.f, 0.f);
            if (mode != 0) {
                // bf16 spo path: 8B/lane rows
                const unsigned short* sb = spo16 + ((size_t)b * NSEQ * NBOX + i) * NCTX;
                ushort4 s0 = ((const ushort4*)(sb + (size_t)e0 * st))[lane];
                ushort4 s1 = ((const ushort4*)(sb + (size_t)e1 * st))[lane];
                ushort4 s2 = ((const ushort4*)(sb + (size_t)e2 * st))[lane];
                for (int n = 0; n < nch; ++n) {
                    const int ep = __shfl(ec, n + 3);   // n+3 <= 26 < 49: active
                    ushort4 nx = ((const ushort4*)(sb + (size_t)ep * st))[lane];
                    a4.x = fmaf(cae[n][mi.x], bf(s0.x), a4.x);
                    a4.y = fmaf(cae[n][mi.y], bf(s0.y), a4.y);
                    a4.z = fmaf(cae[n][mi.z], bf(s0.z), a4.z);
                    a4.w = fmaf(cae[n][mi.w], bf(s0.w), a4.w);
                    s0 = s1; s1 = s2; s2 = nx;
                }
            } else {
                const float* sb = spo + ((size_t)b * NSEQ * NBOX + i) * NCTX;
                float4 s0 = ((const float4*)(sb + (size_t)e0 * st))[lane];
                float4 s1 = ((const float4*)(sb + (size_t)e1 * st))[lane];
                float4 s2 = ((const float4*)(sb + (size_t)e2 * st))[lane];
                for (int n = 0; n < nch; ++n) {
                    const int ep = __shfl(ec, n + 3);
                    float4 nx = ((const float4*)(sb + (size_t)ep * st))[lane];
                    a4.x = fmaf(cae[n][mi.x], s0.x, a4.x);
                    a4.y = fmaf(cae[n][mi.y], s0.y, a4.y);
                    a4.z = fmaf(cae[n][mi.z], s0.z, a4.z);
                    a4.w = fmaf(cae[n][mi.w], s0.w, a4.w);
                    s0 = s1; s1 = s2; s2 = nx;
                }
            }
            acc = (a4.x + a4.y) + (a4.z + a4.w);
        }
        #pragma unroll
        for (int off = 32; off >= 1; off >>= 1)
            acc += __shfl_down(acc, off, 64);
        if (lane == 0) {
            float kci = (roi_cls[b * NBOX + i] != -1) ? 1.0f : 0.0f;
            araw[b * NBOX + i] = kci * acc;
        }
    }
}

// ------------------------------------------------- per-step: finalize + write
__global__ __launch_bounds__(256) void step_finalize(
    float*       __restrict__ ea,       // [BS,NSEQ,NBOX] in/out
    const float* __restrict__ araw,     // ws [BS,NBOX]
    const float* __restrict__ wc,       // [BS,NSEQ,NBOX]
    const int*   __restrict__ roi_cls,  // [BS,NBOX]
    const int*   __restrict__ trav,     // [BS,MAXLEN]
    const int*   __restrict__ adj,      // [BS,NSEQ,NSEQ]
    int step)
{
    const int b   = blockIdx.x;
    const int tid = threadIdx.x;
    const int p   = trav[b * MAXLEN + step];

    int nch = 0;
    if (p >= 0) {
        const int* arow = adj + ((size_t)b * NSEQ + p) * NSEQ;
        for (int j = 0; j < NSEQ; ++j) nch += (arow[j] >= 0) ? 1 : 0;
    }
    if (p < 0 || nch == 0) return;  // row stays unchanged

    float upd = 0.0f, a = 0.0f;
    if (tid < NBOX) {
        const float sub = ea[((size_t)b * NSEQ + p) * NBOX + tid];
        const float w   = wc[((size_t)b * NSEQ + p) * NBOX + tid];
        upd = sub + (araw[b * NBOX + tid] + (float)nch * EPSV) * w;
        a = fabsf(upd);
    }
    #pragma unroll
    for (int off = 32; off >= 1; off >>= 1)
        a = fmaxf(a, __shfl_down(a, off, 64));
    __shared__ float wmax[4];
    if ((tid & 63) == 0) wmax[tid >> 6] = a;
    __syncthreads();
    float norm = fmaxf(fmaxf(wmax[0], wmax[1]), fmaxf(wmax[2], wmax[3]));
    norm = (norm <= 1.0f) ? 1.0f : norm;
    if (tid < NBOX) {
        float val = upd / norm;
        if (roi_cls[b * NBOX + tid] == -1) val = -1.0f;
        ea[((size_t)b * NSEQ + p) * NBOX + tid] = val;
    }
}

extern "C" void kernel_launch(void* const* d_in, const int* in_sizes, int n_in,
                              void* d_out, int out_size, void* d_ws, size_t ws_size,
                              hipStream_t stream) {
    const int*   trav = (const int*)  d_in[0];
    const int*   adj  = (const int*)  d_in[1];
    const float* ent  = (const float*)d_in[2];
    const float* spo  = (const float*)d_in[3];
    const int*   ctx  = (const int*)  d_in[4];
    const int*   roi  = (const int*)  d_in[5];
    const float* rm   = (const float*)d_in[6];
    const float* wc   = (const float*)d_in[7];

    float* ea = (float*)d_out;

    const size_t need = SPO16_B + MIDX_B + ARAW_B;
    const bool ws_ok = ws_size >= need;

    unsigned short* spo16;
    unsigned char*  midx;
    float*          araw;
    if (ws_ok) {
        spo16 = (unsigned short*)d_ws;
        midx  = (unsigned char*)d_ws + SPO16_B;
        araw  = (float*)((char*)d_ws + SPO16_B + MIDX_B);
        conv_spo<<<2048, 256, 0, stream>>>(spo, spo16);
    } else {
        spo16 = (unsigned short*)d_ws;   // unused in mode 0
        midx  = (unsigned char*)d_ws;    // unused in mode 0
        araw  = (float*)d_ws;
    }

    for (int t = 0; t < MAXLEN; ++t) {
        const int mode = ws_ok ? (t == 0 ? 1 : 2) : 0;
        step_compute<<<BS * TILES, K1T, 0, stream>>>(
            t == 0 ? ent : ea, ea, spo, spo16, ctx, roi, rm, trav, adj,
            midx, araw, t, mode);
        step_finalize<<<BS, 256, 0, stream>>>(
            ea, araw, wc, roi, trav, adj, t);
    }
}

// Round 12
// 101.131 us; speedup vs baseline: 1.1936x; 1.1936x over previous
//
#include <hip/hip_runtime.h>

#define NSEQ   24
#define NBOX   196
#define NCTX   196
#define MAXLEN 6
#define EPSV   1e-6f
#define BS     32

#define TILES  25    // i-tiles per batch; 8 waves/block, 1 i per wave
#define K1T    512
#define NB4    49    // float4 chunks per 196-row
#define ROWP   200   // padded cae row: 196 data + 4 zeros (sentinel idx 196)

// ws layout: midx u8 [BS*NBOX*NCTX] | araw f32 [BS*NBOX]
#define MIDX_BYTES ((size_t)BS * NBOX * NCTX)   // 1,229,312 B (16-aligned)

// mode: 0 = compute midx from ctx+rm (no store)   [fallback if ws tiny]
//       1 = compute and store u8 midx (step 0)
//       2 = load u8 midx (steps 1..5)
__global__ __launch_bounds__(K1T, 6) void step_compute(
    const float* __restrict__ src,      // ent (step 0) or ea
    float*       __restrict__ ea,       // [BS,NSEQ,NBOX] (d_out)
    const float* __restrict__ spo,      // [BS,NSEQ,NBOX,NCTX]
    const int*   __restrict__ ctx,      // [BS,NBOX,NCTX]
    const int*   __restrict__ roi_cls,  // [BS,NBOX]
    const float* __restrict__ rm,       // [BS,NBOX,NCTX]
    const int*   __restrict__ trav,     // [BS,MAXLEN]
    const int*   __restrict__ adj,      // [BS,NSEQ,NSEQ]
    unsigned char* __restrict__ midx,   // ws
    float*       __restrict__ araw,     // ws [BS,NBOX]
    int step, int mode)
{
    const int b    = blockIdx.x / TILES;
    const int tile = blockIdx.x % TILES;
    const int tid  = threadIdx.x;
    const int wave = tid >> 6;
    const int lane = tid & 63;

    __shared__ __align__(16) float cae[NSEQ][ROWP];
    __shared__ int s_childJ[NSEQ];

    // ---- fused ent -> ea copy (step 0; nothing reads ea this dispatch)
    if (step == 0) {
        const int total4 = BS * NSEQ * NBOX / 4;
        int idx = blockIdx.x * K1T + tid;
        if (idx < total4) ((float4*)ea)[idx] = ((const float4*)src)[idx];
    }

    // ---- wave-parallel adjacency parse (full exec)
    const int p = trav[b * MAXLEN + step];
    int e = -1;
    if (p >= 0 && lane < NSEQ)
        e = adj[((size_t)b * NSEQ + p) * NSEQ + lane];
    const unsigned long long mask = __ballot(e >= 0);
    const int nch = __popcll(mask);
    int ec = 0;
    if (nch > 0) {
        unsigned long long m = mask;
        const int lim = (lane < NSEQ) ? lane : NSEQ;
        for (int k = 0; k < lim; ++k) m &= (m - 1);
        const int j0 = __ffsll(mask) - 1;
        const int jn = m ? (__ffsll(m) - 1) : j0;
        const int jc = (lane < nch) ? jn : j0;   // lanes >= nch: child 0 (pad)
        ec = __shfl(e, jc);                      // full-exec shfl: safe
        if (wave == 0 && lane < nch) s_childJ[lane] = jc;
    }

    // ---- per-wave i; mask-index vector (built/stored/loaded BEFORE any return
    //      so step-0 writes midx for all i even when nch==0)
    const int i = tile * 8 + wave;
    int4 mi = make_int4(NBOX, NBOX, NBOX, NBOX);
    if (i < NBOX && lane < NB4) {
        const size_t bi = (size_t)b * NBOX + i;
        if (mode == 2) {
            const uchar4 u = ((const uchar4*)(midx + bi * NCTX))[lane];
            mi = make_int4(u.x, u.y, u.z, u.w);
        } else {
            const int4   ix = ((const int4*)  (ctx + bi * NCTX))[lane];
            const float4 m4 = ((const float4*)(rm  + bi * NCTX))[lane];
            mi.x = (m4.x != 0.f) ? ix.x : NBOX;
            mi.y = (m4.y != 0.f) ? ix.y : NBOX;
            mi.z = (m4.z != 0.f) ? ix.z : NBOX;
            mi.w = (m4.w != 0.f) ? ix.w : NBOX;
            if (mode == 1)
                ((uchar4*)(midx + bi * NCTX))[lane] =
                    make_uchar4((unsigned char)mi.x, (unsigned char)mi.y,
                                (unsigned char)mi.z, (unsigned char)mi.w);
        }
    }

    if (nch == 0) return;   // uniform across block; no barrier crossed yet

    // ---- EARLY spo prefetch: s0..s2 depend only on registers (ec), not on
    //      staged LDS — issue them BEFORE staging so their latency hides
    //      under the child-row staging loads instead of after the barrier.
    const float* sb = spo + ((size_t)b * NSEQ * NBOX + i) * NCTX;
    const size_t st = (size_t)NBOX * NCTX;
    float4 s0, s1, s2;
    if (i < NBOX) {                                  // wave-uniform guard
        const int e0 = __shfl(ec, 0), e1 = __shfl(ec, 1), e2 = __shfl(ec, 2);
        if (lane < NB4) {
            s0 = ((const float4*)(sb + (size_t)e0 * st))[lane];
            s1 = ((const float4*)(sb + (size_t)e1 * st))[lane];
            s2 = ((const float4*)(sb + (size_t)e2 * st))[lane];
        }
    }

    __syncthreads();        // s_childJ visible

    // ---- stage child rows * kcls into LDS (float4; quad 49 writes zero pad)
    for (int n = wave; n < nch; n += 8) {
        const int j = s_childJ[n];
        if (lane < 50) {
            float4 v = make_float4(0.f, 0.f, 0.f, 0.f);
            if (lane < NB4) {
                const float4 e4 = ((const float4*)(src + ((size_t)b * NSEQ + j) * NBOX))[lane];
                const int4   r4 = ((const int4*)(roi_cls + b * NBOX))[lane];
                v.x = (r4.x != -1) ? e4.x : 0.f;
                v.y = (r4.y != -1) ? e4.y : 0.f;
                v.z = (r4.z != -1) ? e4.z : 0.f;
                v.w = (r4.w != -1) ? e4.w : 0.f;
            }
            ((float4*)&cae[n][0])[lane] = v;
        }
    }
    __syncthreads();

    // ---- gather-dot: one i per wave, 3-deep rotating spo prefetch
    if (i < NBOX) {
        float acc = 0.f;
        if (lane < NB4) {
            float4 a4 = make_float4(0.f, 0.f, 0.f, 0.f);
            for (int n = 0; n < nch; ++n) {
                const int ep = __shfl(ec, n + 3);   // n+3 <= 26 < 49: active lane
                float4 nx = ((const float4*)(sb + (size_t)ep * st))[lane];
                a4.x = fmaf(cae[n][mi.x], s0.x, a4.x);
                a4.y = fmaf(cae[n][mi.y], s0.y, a4.y);
                a4.z = fmaf(cae[n][mi.z], s0.z, a4.z);
                a4.w = fmaf(cae[n][mi.w], s0.w, a4.w);
                s0 = s1; s1 = s2; s2 = nx;
            }
            acc = (a4.x + a4.y) + (a4.z + a4.w);
        }
        #pragma unroll
        for (int off = 32; off >= 1; off >>= 1)
            acc += __shfl_down(acc, off, 64);
        if (lane == 0) {
            float kci = (roi_cls[b * NBOX + i] != -1) ? 1.0f : 0.0f;
            araw[b * NBOX + i] = kci * acc;
        }
    }
}

// ------------------------------------------------- per-step: finalize + write
__global__ __launch_bounds__(256) void step_finalize(
    float*       __restrict__ ea,       // [BS,NSEQ,NBOX] in/out
    const float* __restrict__ araw,     // ws [BS,NBOX]
    const float* __restrict__ wc,       // [BS,NSEQ,NBOX]
    const int*   __restrict__ roi_cls,  // [BS,NBOX]
    const int*   __restrict__ trav,     // [BS,MAXLEN]
    const int*   __restrict__ adj,      // [BS,NSEQ,NSEQ]
    int step)
{
    const int b   = blockIdx.x;
    const int tid = threadIdx.x;
    const int p   = trav[b * MAXLEN + step];

    int nch = 0;
    if (p >= 0) {
        const int* arow = adj + ((size_t)b * NSEQ + p) * NSEQ;
        for (int j = 0; j < NSEQ; ++j) nch += (arow[j] >= 0) ? 1 : 0;
    }
    if (p < 0 || nch == 0) return;  // row stays unchanged

    float upd = 0.0f, a = 0.0f;
    if (tid < NBOX) {
        const float sub = ea[((size_t)b * NSEQ + p) * NBOX + tid];
        const float w   = wc[((size_t)b * NSEQ + p) * NBOX + tid];
        upd = sub + (araw[b * NBOX + tid] + (float)nch * EPSV) * w;
        a = fabsf(upd);
    }
    #pragma unroll
    for (int off = 32; off >= 1; off >>= 1)
        a = fmaxf(a, __shfl_down(a, off, 64));
    __shared__ float wmax[4];
    if ((tid & 63) == 0) wmax[tid >> 6] = a;
    __syncthreads();
    float norm = fmaxf(fmaxf(wmax[0], wmax[1]), fmaxf(wmax[2], wmax[3]));
    norm = (norm <= 1.0f) ? 1.0f : norm;
    if (tid < NBOX) {
        float val = upd / norm;
        if (roi_cls[b * NBOX + tid] == -1) val = -1.0f;
        ea[((size_t)b * NSEQ + p) * NBOX + tid] = val;
    }
}

extern "C" void kernel_launch(void* const* d_in, const int* in_sizes, int n_in,
                              void* d_out, int out_size, void* d_ws, size_t ws_size,
                              hipStream_t stream) {
    const int*   trav = (const int*)  d_in[0];
    const int*   adj  = (const int*)  d_in[1];
    const float* ent  = (const float*)d_in[2];
    const float* spo  = (const float*)d_in[3];
    const int*   ctx  = (const int*)  d_in[4];
    const int*   roi  = (const int*)  d_in[5];
    const float* rm   = (const float*)d_in[6];
    const float* wc   = (const float*)d_in[7];

    float* ea = (float*)d_out;

    const size_t need = MIDX_BYTES + (size_t)BS * NBOX * 4;
    const bool ws_ok = ws_size >= need;
    unsigned char* midx = (unsigned char*)d_ws;
    float* araw = ws_ok ? (float*)((char*)d_ws + MIDX_BYTES) : (float*)d_ws;

    for (int t = 0; t < MAXLEN; ++t) {
        const int mode = ws_ok ? (t == 0 ? 1 : 2) : 0;
        step_compute<<<BS * TILES, K1T, 0, stream>>>(
            t == 0 ? ent : ea, ea, spo, ctx, roi, rm, trav, adj,
            midx, araw, t, mode);
        step_finalize<<<BS, 256, 0, stream>>>(
            ea, araw, wc, roi, trav, adj, t);
    }
}

// Round 14
// 99.709 us; speedup vs baseline: 1.2107x; 1.0143x over previous
//
#include <hip/hip_runtime.h>

#define NSEQ   24
#define NBOX   196
#define NCTX   196
#define MAXLEN 6
#define EPSV   1e-6f
#define BS     32

#define TILES  25    // i-tiles per batch; 8 waves/block, 1 i per wave
#define K1T    512
#define NB4    49    // float4 chunks per 196-row
#define ROWP   200   // padded cae row: 196 data + 4 zeros (sentinel idx 196)

// ws layout: midx u8 [BS*NBOX*NCTX] | araw f32 [BS*NBOX]
#define MIDX_BYTES ((size_t)BS * NBOX * NCTX)   // 1,229,312 B (16-aligned)

// mode: 0 = compute midx from ctx+rm (no store)   [fallback if ws tiny]
//       1 = compute and store u8 midx (step 0)
//       2 = load u8 midx (steps 1..5)
__global__ __launch_bounds__(K1T, 6) void step_compute(
    const float* __restrict__ src,      // ent (step 0) or ea
    float*       __restrict__ ea,       // [BS,NSEQ,NBOX] (d_out)
    const float* __restrict__ spo,      // [BS,NSEQ,NBOX,NCTX]
    const int*   __restrict__ ctx,      // [BS,NBOX,NCTX]
    const int*   __restrict__ roi_cls,  // [BS,NBOX]
    const float* __restrict__ rm,       // [BS,NBOX,NCTX]
    const int*   __restrict__ trav,     // [BS,MAXLEN]
    const int*   __restrict__ adj,      // [BS,NSEQ,NSEQ]
    unsigned char* __restrict__ midx,   // ws
    float*       __restrict__ araw,     // ws [BS,NBOX]
    int step, int mode)
{
    const int b    = blockIdx.x / TILES;
    const int tile = blockIdx.x % TILES;
    const int tid  = threadIdx.x;
    const int wave = tid >> 6;
    const int lane = tid & 63;

    __shared__ __align__(16) float cae[NSEQ][ROWP];
    __shared__ int s_childJ[NSEQ];

    // ---- fused ent -> ea copy (step 0; nothing reads ea this dispatch)
    if (step == 0) {
        const int total4 = BS * NSEQ * NBOX / 4;
        int idx = blockIdx.x * K1T + tid;
        if (idx < total4) ((float4*)ea)[idx] = ((const float4*)src)[idx];
    }

    // ---- wave-parallel adjacency parse (full exec)
    const int p = trav[b * MAXLEN + step];
    int e = -1;
    if (p >= 0 && lane < NSEQ)
        e = adj[((size_t)b * NSEQ + p) * NSEQ + lane];
    const unsigned long long mask = __ballot(e >= 0);
    const int nch = __popcll(mask);
    int ec = 0;
    if (nch > 0) {
        unsigned long long m = mask;
        const int lim = (lane < NSEQ) ? lane : NSEQ;
        for (int k = 0; k < lim; ++k) m &= (m - 1);
        const int j0 = __ffsll(mask) - 1;
        const int jn = m ? (__ffsll(m) - 1) : j0;
        const int jc = (lane < nch) ? jn : j0;   // lanes >= nch: child 0 (pad)
        ec = __shfl(e, jc);                      // full-exec shfl: safe
        if (wave == 0 && lane < nch) s_childJ[lane] = jc;
    }

    // ---- per-wave i; mask-index vector (built/stored/loaded BEFORE any return
    //      so step-0 writes midx for all i even when nch==0)
    const int i = tile * 8 + wave;
    int4 mi = make_int4(NBOX, NBOX, NBOX, NBOX);
    if (i < NBOX && lane < NB4) {
        const size_t bi = (size_t)b * NBOX + i;
        if (mode == 2) {
            const uchar4 u = ((const uchar4*)(midx + bi * NCTX))[lane];
            mi = make_int4(u.x, u.y, u.z, u.w);
        } else {
            const int4   ix = ((const int4*)  (ctx + bi * NCTX))[lane];
            const float4 m4 = ((const float4*)(rm  + bi * NCTX))[lane];
            mi.x = (m4.x != 0.f) ? ix.x : NBOX;
            mi.y = (m4.y != 0.f) ? ix.y : NBOX;
            mi.z = (m4.z != 0.f) ? ix.z : NBOX;
            mi.w = (m4.w != 0.f) ? ix.w : NBOX;
            if (mode == 1)
                ((uchar4*)(midx + bi * NCTX))[lane] =
                    make_uchar4((unsigned char)mi.x, (unsigned char)mi.y,
                                (unsigned char)mi.z, (unsigned char)mi.w);
        }
    }

    if (nch == 0) return;   // uniform across block; no barrier crossed yet

    __syncthreads();        // s_childJ visible

    // ---- stage child rows * kcls into LDS (float4; quad 49 writes zero pad)
    for (int n = wave; n < nch; n += 8) {
        const int j = s_childJ[n];
        if (lane < 50) {
            float4 v = make_float4(0.f, 0.f, 0.f, 0.f);
            if (lane < NB4) {
                const float4 e4 = ((const float4*)(src + ((size_t)b * NSEQ + j) * NBOX))[lane];
                const int4   r4 = ((const int4*)(roi_cls + b * NBOX))[lane];
                v.x = (r4.x != -1) ? e4.x : 0.f;
                v.y = (r4.y != -1) ? e4.y : 0.f;
                v.z = (r4.z != -1) ? e4.z : 0.f;
                v.w = (r4.w != -1) ? e4.w : 0.f;
            }
            ((float4*)&cae[n][0])[lane] = v;
        }
    }
    __syncthreads();

    // ---- gather-dot: one i per wave, 3-deep rotating spo prefetch
    if (i < NBOX) {
        float acc = 0.f;
        if (lane < NB4) {
            const float* sb = spo + ((size_t)b * NSEQ * NBOX + i) * NCTX;
            const size_t st = (size_t)NBOX * NCTX;
            const int e0 = __shfl(ec, 0), e1 = __shfl(ec, 1), e2 = __shfl(ec, 2);
            float4 s0 = ((const float4*)(sb + (size_t)e0 * st))[lane];
            float4 s1 = ((const float4*)(sb + (size_t)e1 * st))[lane];
            float4 s2 = ((const float4*)(sb + (size_t)e2 * st))[lane];
            float4 a4 = make_float4(0.f, 0.f, 0.f, 0.f);
            for (int n = 0; n < nch; ++n) {
                const int ep = __shfl(ec, n + 3);   // n+3 <= 26 < 49: active lane
                float4 nx = ((const float4*)(sb + (size_t)ep * st))[lane];
                a4.x = fmaf(cae[n][mi.x], s0.x, a4.x);
                a4.y = fmaf(cae[n][mi.y], s0.y, a4.y);
                a4.z = fmaf(cae[n][mi.z], s0.z, a4.z);
                a4.w = fmaf(cae[n][mi.w], s0.w, a4.w);
                s0 = s1; s1 = s2; s2 = nx;
            }
            acc = (a4.x + a4.y) + (a4.z + a4.w);
        }
        #pragma unroll
        for (int off = 32; off >= 1; off >>= 1)
            acc += __shfl_down(acc, off, 64);
        if (lane == 0) {
            float kci = (roi_cls[b * NBOX + i] != -1) ? 1.0f : 0.0f;
            araw[b * NBOX + i] = kci * acc;
        }
    }
}

// ------------------------------------------------- per-step: finalize + write
// sub_src: ent at step 0 (bit-identical to ea there — the copy just made
// ea[b,p]==ent[b,p] — but avoids reading a line written ~1us earlier),
// ea for steps >= 1.
__global__ __launch_bounds__(256) void step_finalize(
    float*       __restrict__ ea,       // [BS,NSEQ,NBOX] out
    const float* __restrict__ sub_src,  // ent (step 0) or ea
    const float* __restrict__ araw,     // ws [BS,NBOX]
    const float* __restrict__ wc,       // [BS,NSEQ,NBOX]
    const int*   __restrict__ roi_cls,  // [BS,NBOX]
    const int*   __restrict__ trav,     // [BS,MAXLEN]
    const int*   __restrict__ adj,      // [BS,NSEQ,NSEQ]
    int step)
{
    const int b   = blockIdx.x;
    const int tid = threadIdx.x;
    const int p   = trav[b * MAXLEN + step];

    int nch = 0;
    if (p >= 0) {
        const int* arow = adj + ((size_t)b * NSEQ + p) * NSEQ;
        for (int j = 0; j < NSEQ; ++j) nch += (arow[j] >= 0) ? 1 : 0;
    }
    if (p < 0 || nch == 0) return;  // row stays unchanged

    float upd = 0.0f, a = 0.0f;
    if (tid < NBOX) {
        const float sub = sub_src[((size_t)b * NSEQ + p) * NBOX + tid];
        const float w   = wc[((size_t)b * NSEQ + p) * NBOX + tid];
        upd = sub + (araw[b * NBOX + tid] + (float)nch * EPSV) * w;
        a = fabsf(upd);
    }
    #pragma unroll
    for (int off = 32; off >= 1; off >>= 1)
        a = fmaxf(a, __shfl_down(a, off, 64));
    __shared__ float wmax[4];
    if ((tid & 63) == 0) wmax[tid >> 6] = a;
    __syncthreads();
    float norm = fmaxf(fmaxf(wmax[0], wmax[1]), fmaxf(wmax[2], wmax[3]));
    norm = (norm <= 1.0f) ? 1.0f : norm;
    if (tid < NBOX) {
        float val = upd / norm;
        if (roi_cls[b * NBOX + tid] == -1) val = -1.0f;
        ea[((size_t)b * NSEQ + p) * NBOX + tid] = val;
    }
}

extern "C" void kernel_launch(void* const* d_in, const int* in_sizes, int n_in,
                              void* d_out, int out_size, void* d_ws, size_t ws_size,
                              hipStream_t stream) {
    const int*   trav = (const int*)  d_in[0];
    const int*   adj  = (const int*)  d_in[1];
    const float* ent  = (const float*)d_in[2];
    const float* spo  = (const float*)d_in[3];
    const int*   ctx  = (const int*)  d_in[4];
    const int*   roi  = (const int*)  d_in[5];
    const float* rm   = (const float*)d_in[6];
    const float* wc   = (const float*)d_in[7];

    float* ea = (float*)d_out;

    const size_t need = MIDX_BYTES + (size_t)BS * NBOX * 4;
    const bool ws_ok = ws_size >= need;
    unsigned char* midx = (unsigned char*)d_ws;
    float* araw = ws_ok ? (float*)((char*)d_ws + MIDX_BYTES) : (float*)d_ws;

    for (int t = 0; t < MAXLEN; ++t) {
        const int mode = ws_ok ? (t == 0 ? 1 : 2) : 0;
        step_compute<<<BS * TILES, K1T, 0, stream>>>(
            t == 0 ? ent : ea, ea, spo, ctx, roi, rm, trav, adj,
            midx, araw, t, mode);
        step_finalize<<<BS, 256, 0, stream>>>(
            ea, t == 0 ? ent : ea, araw, wc, roi, trav, adj, t);
    }
}